// Round 6
// baseline (400.762 us; speedup 1.0000x reference)
//
#include <hip/hip_runtime.h>

#define N_NODES 100000
#define N_EDGES 1600000
#define IN_DIM 128
#define HID 64
#define NB 782               // ceil(100000 / 128) buckets of 128 nodes
#define NBLK_GEMM 782        // ceil(100000 / 128) gemm blocks (128 rows each)
#define NGROUP16 6250        // N_NODES / 16 fused-agg blocks

typedef __attribute__((ext_vector_type(8))) _Float16 h8v;
typedef __attribute__((ext_vector_type(4))) float f4v;

struct Args {
  const float* x; const int* ei;
  const float* Wp; const float* bp;
  const float* W1; const float* b1;
  const float* W2; const float* b2;
  const float* W3; const float* b3;
  float* out;
  _Float16* bufA16; _Float16* hw16;
  int* pairs; int* csr; int* offs; float* dinv;
  int* bsz; int* bboff; int* bcur;
  _Float16* WpH; _Float16* WpL; _Float16* W1H; _Float16* W1L;
  _Float16* W2H; _Float16* W2L; _Float16* W3H; _Float16* W3L;
};

// f16(lo/hi half of dword) * f32 + f32 accumulate, single VALU op
__device__ __forceinline__ void fmix_lo(float& acc, unsigned hv, float w) {
  asm("v_fma_mix_f32 %0, %1, %2, %0 op_sel:[0,0,0] op_sel_hi:[1,0,0]"
      : "+v"(acc) : "v"(hv), "v"(w));
}
__device__ __forceinline__ void fmix_hi(float& acc, unsigned hv, float w) {
  asm("v_fma_mix_f32 %0, %1, %2, %0 op_sel:[1,0,0] op_sel_hi:[1,0,0]"
      : "+v"(acc) : "v"(hv), "v"(w));
}

// ---------------- weight prep: split fp32 W[K][64] -> transposed half hi/lo ----
__device__ __forceinline__ void d_split(const float* __restrict__ W,
                                        _Float16* __restrict__ hi,
                                        _Float16* __restrict__ lo, int K, int i) {
  int k = i >> 6, n = i & 63;
  float v = W[i];
  _Float16 h = (_Float16)v;
  float r = v - (float)h;
  hi[n * K + k] = h;
  lo[n * K + k] = (_Float16)r;
}

__global__ __launch_bounds__(256) void f_prep(Args a) {
  int blk = blockIdx.x, t = threadIdx.x;
  if (blk < 32) d_split(a.Wp, a.WpH, a.WpL, IN_DIM, blk * 256 + t);
  else if (blk < 48) d_split(a.W1, a.W1H, a.W1L, HID, (blk - 32) * 256 + t);
  else if (blk < 64) d_split(a.W2, a.W2H, a.W2L, HID, (blk - 48) * 256 + t);
  else d_split(a.W3, a.W3H, a.W3L, HID, (blk - 64) * 256 + t);
}

// ---------------- bucket histogram ----------------
__global__ __launch_bounds__(256) void f_bhist(Args a) {
  __shared__ int cnt[NB];
  int t = threadIdx.x;
  for (int i = t; i < NB; i += 256) cnt[i] = 0;
  __syncthreads();
  int e0 = blockIdx.x * 8192, e1 = min(e0 + 8192, N_EDGES);
  for (int e = e0 + t; e < e1; e += 256)
    atomicAdd(&cnt[a.ei[N_EDGES + e] >> 7], 1);
  __syncthreads();
  for (int i = t; i < NB; i += 256)
    if (cnt[i]) atomicAdd(&a.bsz[i], cnt[i]);
}

// ---------------- bucket exclusive scan (1 block, 256 thr x 4 slots) ----------
__global__ __launch_bounds__(256) void f_bscan(Args a) {
  __shared__ int sm[256];
  int t = threadIdx.x;
  int c[4];
  int idx0 = t * 4;
#pragma unroll
  for (int j = 0; j < 4; ++j) c[j] = (idx0 + j < NB) ? a.bsz[idx0 + j] : 0;
  int tsum = c[0] + c[1] + c[2] + c[3];
  int val = tsum;
  sm[t] = val;
  __syncthreads();
  for (int off = 1; off < 256; off <<= 1) {
    int u = (t >= off) ? sm[t - off] : 0;
    __syncthreads();
    val += u;
    sm[t] = val;
    __syncthreads();
  }
  int excl = val - tsum;
#pragma unroll
  for (int j = 0; j < 4; ++j) {
    int idx = idx0 + j;
    if (idx < NB) { a.bboff[idx] = excl; a.bcur[idx] = excl; }
    excl += c[j];
  }
  if (t == 255) a.bboff[NB] = val;  // == N_EDGES
}

// ---------------- partition edges into buckets; pack (dlocal<<17 | src) --------
__global__ __launch_bounds__(256) void f_partition(Args a) {
  __shared__ int cnt[NB];
  __shared__ int base[NB];
  int t = threadIdx.x;
  for (int i = t; i < NB; i += 256) cnt[i] = 0;
  __syncthreads();
  int e0 = blockIdx.x * 8192, e1 = min(e0 + 8192, N_EDGES);
  for (int e = e0 + t; e < e1; e += 256)
    atomicAdd(&cnt[a.ei[N_EDGES + e] >> 7], 1);
  __syncthreads();
  for (int i = t; i < NB; i += 256) {
    int c = cnt[i];
    base[i] = c ? atomicAdd(&a.bcur[i], c) : 0;
    cnt[i] = 0;
  }
  __syncthreads();
  for (int e = e0 + t; e < e1; e += 256) {
    int s = a.ei[e];
    int d = a.ei[N_EDGES + e];
    int b = d >> 7;
    int r = atomicAdd(&cnt[b], 1);
    a.pairs[base[b] + r] = ((d & 127) << 17) | s;
  }
}

// ---------------- per-bucket degrees + offs + dinv + CSR scatter ---------------
// csr stores src << 7 (byte offset of the 128B fp16 row)
__global__ __launch_bounds__(256) void f_csrdeg(Args a) {
  __shared__ int ldeg[128];
  __shared__ int sc[128];
  __shared__ int lcur[128];
  int t = threadIdx.x;
  int b = blockIdx.x;
  int node0 = b << 7;
  int nloc = min(128, N_NODES - node0);
  int beg = a.bboff[b], end = a.bboff[b + 1];
  if (t < 128) ldeg[t] = 0;
  __syncthreads();
  for (int i = beg + t; i < end; i += 256)
    atomicAdd(&ldeg[(a.pairs[i] >> 17) & 127], 1);
  __syncthreads();
  int dv = (t < 128) ? ldeg[t] : 0;
  if (t < 128) sc[t] = dv;
  __syncthreads();
  for (int off = 1; off < 128; off <<= 1) {
    int u = (t >= off && t < 128) ? sc[t - off] : 0;
    __syncthreads();
    if (t < 128) sc[t] += u;
    __syncthreads();
  }
  if (t < nloc) {
    int o = beg + sc[t] - dv;
    a.offs[node0 + t] = o;
    lcur[t] = o;
    a.dinv[node0 + t] = rsqrtf((float)dv + 1.0f);
  }
  if (b == NB - 1 && t == 0) a.offs[N_NODES] = N_EDGES;
  __syncthreads();
  for (int i = beg + t; i < end; i += 256) {
    int p = a.pairs[i];
    int pos = atomicAdd(&lcur[(p >> 17) & 127], 1);
    a.csr[pos] = (p & 131071) << 7;
  }
}

// ---- pre GEMM v2: LDS-staged swizzled weights, 2 frags/wave, dbuf x prefetch ----
__global__ __launch_bounds__(256) void f_gemm_pre(Args a) {
  __shared__ _Float16 sW[2 * 64 * IN_DIM];  // hi | lo halves, XOR-swizzled (32 KB)
  int t = threadIdx.x;
  int wave = t >> 6, lane = t & 63, fi = lane & 15, quad = lane >> 4;
  int r0 = blockIdx.x * 128 + wave * 32;

  f4v xb0[8], xb1[8];
  {
    int row = r0 + fi; if (row >= N_NODES) row = N_NODES - 1;
    const float* xp = a.x + (size_t)row * IN_DIM + quad * 8;
#pragma unroll
    for (int j = 0; j < 4; ++j) {
      xb0[2 * j]     = *(const f4v*)(xp + j * 32);
      xb0[2 * j + 1] = *(const f4v*)(xp + j * 32 + 4);
    }
  }
#pragma unroll
  for (int i = 0; i < 8; ++i) {
    int c = i * 256 + t;               // 0..2047
    int h = c >> 10;                   // 0 = hi, 1 = lo
    int c2 = c & 1023;                 // chunk within half
    int n = c2 >> 4;                   // output-col row (16 chunks per row)
    const _Float16* src = (h ? a.WpL : a.WpH) + c2 * 8;
    f4v v = *(const f4v*)src;
    int off = (h << 14) | ((c2 * 16) ^ ((n & 7) << 4));
    *(f4v*)((char*)sW + off) = v;
  }
  __syncthreads();

  float bv[4];
#pragma unroll
  for (int ct = 0; ct < 4; ++ct) bv[ct] = a.bp[ct * 16 + fi];

#pragma unroll
  for (int f = 0; f < 2; ++f) {
    f4v* xcur = (f & 1) ? xb1 : xb0;
    f4v* xnxt = (f & 1) ? xb0 : xb1;
    if (f < 1) {
      int row = r0 + 16 + fi; if (row >= N_NODES) row = N_NODES - 1;
      const float* xp = a.x + (size_t)row * IN_DIM + quad * 8;
#pragma unroll
      for (int j = 0; j < 4; ++j) {
        xnxt[2 * j]     = *(const f4v*)(xp + j * 32);
        xnxt[2 * j + 1] = *(const f4v*)(xp + j * 32 + 4);
      }
    }
    f4v acc[4];
#pragma unroll
    for (int ct = 0; ct < 4; ++ct) acc[ct] = (f4v){0.f, 0.f, 0.f, 0.f};
#pragma unroll
    for (int k0i = 0; k0i < 4; ++k0i) {
      h8v ah, al;
#pragma unroll
      for (int j = 0; j < 4; ++j) {
        float v0 = xcur[2 * k0i][j], v1 = xcur[2 * k0i + 1][j];
        _Float16 h0 = (_Float16)v0, h1 = (_Float16)v1;
        ah[j] = h0;     al[j] = (_Float16)(v0 - (float)h0);
        ah[4 + j] = h1; al[4 + j] = (_Float16)(v1 - (float)h1);
      }
#pragma unroll
      for (int ct = 0; ct < 4; ++ct) {
        int n = ct * 16 + fi;
        int bo = ((n * IN_DIM + k0i * 32 + quad * 8) * 2) ^ ((n & 7) << 4);
        h8v bh = *(const h8v*)((const char*)sW + bo);
        h8v bl = *(const h8v*)((const char*)sW + 16384 + bo);
        acc[ct] = __builtin_amdgcn_mfma_f32_16x16x32_f16(ah, bh, acc[ct], 0, 0, 0);
        acc[ct] = __builtin_amdgcn_mfma_f32_16x16x32_f16(al, bh, acc[ct], 0, 0, 0);
        acc[ct] = __builtin_amdgcn_mfma_f32_16x16x32_f16(ah, bl, acc[ct], 0, 0, 0);
      }
    }
    int ro = r0 + f * 16;
#pragma unroll
    for (int ct = 0; ct < 4; ++ct) {
#pragma unroll
      for (int j = 0; j < 4; ++j) {
        int orow = ro + quad * 4 + j;
        if (orow < N_NODES)
          a.bufA16[(size_t)orow * HID + ct * 16 + fi] = (_Float16)(acc[ct][j] + bv[ct]);
      }
    }
  }
}

// ---- fused aggregate + GEMM (v7): 4-node INTERLEAVED gather ------------------
// agg(h W) == (agg h) W. Block = 16 nodes (4 waves x 4 nodes INTERLEAVED).
// Phase 1: each pass issues 8 row-gathers (2 per node x 4 nodes) before the
//   fma_mix consumes them -> 8 loads in flight per wave (vs 2 in v6).
//   Pass count is wave-uniform: ceil(maxdeg/16); drained nodes issue clamped
//   same-line loads with w=0 (L1 hit).
// Phase 2: each wave computes one 16-out-ch tile for all 16 nodes via 6 MFMAs,
//   then bias+relu (MODE 0) or bias+L2 normalize via cross-wave LDS (MODE 1).
template <int MODE>
__global__ __launch_bounds__(256) void f_aggw(Args a, const _Float16* __restrict__ hsrc,
                                              const _Float16* __restrict__ Wh,
                                              const _Float16* __restrict__ Wl,
                                              const float* __restrict__ bias,
                                              _Float16* __restrict__ out16,
                                              float* __restrict__ out32) {
  __shared__ char sG[2][2048];     // [hi|lo][16 rows x 128B], byte ^= (row&7)<<4
  __shared__ float sSS[4][16];     // per-wave partial sum-of-squares (MODE 1)
  int t = threadIdx.x;
  int wave = t >> 6, lane = t & 63, oct = lane >> 3, fi = lane & 7;
  int node0 = blockIdx.x * 16;     // N_NODES == 6250*16, no bounds checks
  const char* hwb = (const char*)hsrc;
  int lb = fi * 16;
  int nb = node0 + wave * 4;

  float di[4];
  int beg[4], end[4];
#pragma unroll
  for (int n = 0; n < 4; ++n) {
    di[n] = a.dinv[nb + n];
    beg[n] = a.offs[nb + n];
    end[n] = a.offs[nb + n + 1];
  }

  float acc[4][8];
#pragma unroll
  for (int n = 0; n < 4; ++n)
#pragma unroll
    for (int c = 0; c < 8; ++c) acc[n][c] = 0.f;

  if (oct == 0) {  // self-loop: h_self * di (post-scale by di -> di^2)
    uint4 hv[4];
#pragma unroll
    for (int n = 0; n < 4; ++n)
      hv[n] = *(const uint4*)(hwb + ((size_t)(nb + n) << 7) + lb);
#pragma unroll
    for (int n = 0; n < 4; ++n) {
      fmix_lo(acc[n][0], hv[n].x, di[n]); fmix_hi(acc[n][1], hv[n].x, di[n]);
      fmix_lo(acc[n][2], hv[n].y, di[n]); fmix_hi(acc[n][3], hv[n].y, di[n]);
      fmix_lo(acc[n][4], hv[n].z, di[n]); fmix_hi(acc[n][5], hv[n].z, di[n]);
      fmix_lo(acc[n][6], hv[n].w, di[n]); fmix_hi(acc[n][7], hv[n].w, di[n]);
    }
  }

  int e[4];
#pragma unroll
  for (int n = 0; n < 4; ++n) e[n] = beg[n] + oct;
  int maxd = max(max(end[0] - beg[0], end[1] - beg[1]),
                 max(end[2] - beg[2], end[3] - beg[3]));
  int np = (maxd + 15) >> 4;

  for (int p = 0; p < np; ++p) {
    uint4 h0[4], h1[4];
    float w0[4], w1[4];
#pragma unroll
    for (int n = 0; n < 4; ++n) {
      int e0 = e[n];
      bool v0 = e0 < end[n];
      bool v1 = e0 + 8 < end[n];
      int off0 = a.csr[v0 ? e0 : beg[n]];
      int off1 = a.csr[v1 ? e0 + 8 : beg[n]];
      w0[n] = v0 ? a.dinv[(unsigned)off0 >> 7] : 0.0f;
      w1[n] = v1 ? a.dinv[(unsigned)off1 >> 7] : 0.0f;
      h0[n] = *(const uint4*)(hwb + (unsigned)off0 + lb);
      h1[n] = *(const uint4*)(hwb + (unsigned)off1 + lb);
      e[n] += 16;
    }
#pragma unroll
    for (int n = 0; n < 4; ++n) {
      fmix_lo(acc[n][0], h0[n].x, w0[n]); fmix_hi(acc[n][1], h0[n].x, w0[n]);
      fmix_lo(acc[n][2], h0[n].y, w0[n]); fmix_hi(acc[n][3], h0[n].y, w0[n]);
      fmix_lo(acc[n][4], h0[n].z, w0[n]); fmix_hi(acc[n][5], h0[n].z, w0[n]);
      fmix_lo(acc[n][6], h0[n].w, w0[n]); fmix_hi(acc[n][7], h0[n].w, w0[n]);
      fmix_lo(acc[n][0], h1[n].x, w1[n]); fmix_hi(acc[n][1], h1[n].x, w1[n]);
      fmix_lo(acc[n][2], h1[n].y, w1[n]); fmix_hi(acc[n][3], h1[n].y, w1[n]);
      fmix_lo(acc[n][4], h1[n].z, w1[n]); fmix_hi(acc[n][5], h1[n].z, w1[n]);
      fmix_lo(acc[n][6], h1[n].w, w1[n]); fmix_hi(acc[n][7], h1[n].w, w1[n]);
    }
  }

#pragma unroll
  for (int n = 0; n < 4; ++n)
#pragma unroll
    for (int c = 0; c < 8; ++c) {
      float v = acc[n][c];
      v += __shfl_xor(v, 8);
      v += __shfl_xor(v, 16);
      v += __shfl_xor(v, 32);
      acc[n][c] = v;
    }
  if (oct == 0) {  // g = acc * di, split hi/lo, stage to LDS
#pragma unroll
    for (int n = 0; n < 4; ++n) {
      int row = wave * 4 + n;
      h8v gh, gl;
#pragma unroll
      for (int c = 0; c < 8; ++c) {
        float g = acc[n][c] * di[n];
        _Float16 h = (_Float16)g;
        gh[c] = h;
        gl[c] = (_Float16)(g - (float)h);
      }
      int off = (row * 128 + fi * 16) ^ ((row & 7) << 4);
      *(h8v*)(&sG[0][0] + off) = gh;
      *(h8v*)(&sG[1][0] + off) = gl;
    }
  }
  __syncthreads();

  // MFMA phase: wave w -> out-ch tile [w*16, w*16+16) for all 16 nodes
  int r15 = lane & 15, quad = lane >> 4;
  f4v acc4 = {0.f, 0.f, 0.f, 0.f};
#pragma unroll
  for (int k0i = 0; k0i < 2; ++k0i) {
    int ao = (r15 * 128 + k0i * 64 + quad * 16) ^ ((r15 & 7) << 4);
    h8v ah = *(const h8v*)(&sG[0][0] + ao);
    h8v al = *(const h8v*)(&sG[1][0] + ao);
    size_t bo = (size_t)(wave * 16 + r15) * HID + k0i * 32 + quad * 8;
    h8v bh = *(const h8v*)(Wh + bo);
    h8v bl = *(const h8v*)(Wl + bo);
    acc4 = __builtin_amdgcn_mfma_f32_16x16x32_f16(ah, bh, acc4, 0, 0, 0);
    acc4 = __builtin_amdgcn_mfma_f32_16x16x32_f16(al, bh, acc4, 0, 0, 0);
    acc4 = __builtin_amdgcn_mfma_f32_16x16x32_f16(ah, bl, acc4, 0, 0, 0);
  }
  // C layout: node = quad*4 + j (block-local), out-ch = wave*16 + r15
  float bv = bias[wave * 16 + r15];
  if (MODE == 0) {
#pragma unroll
    for (int j = 0; j < 4; ++j) {
      int nl = quad * 4 + j;
      out16[(size_t)(node0 + nl) * HID + wave * 16 + r15] =
          (_Float16)fmaxf(acc4[j] + bv, 0.f);
    }
  } else {
    float val[4], ssj[4];
#pragma unroll
    for (int j = 0; j < 4; ++j) { val[j] = acc4[j] + bv; ssj[j] = val[j] * val[j]; }
#pragma unroll
    for (int m = 1; m < 16; m <<= 1) {
#pragma unroll
      for (int j = 0; j < 4; ++j) ssj[j] += __shfl_xor(ssj[j], m);
    }
    if (r15 == 0) {
#pragma unroll
      for (int j = 0; j < 4; ++j) sSS[wave][quad * 4 + j] = ssj[j];
    }
    __syncthreads();
#pragma unroll
    for (int j = 0; j < 4; ++j) {
      int nl = quad * 4 + j;
      float tot = sSS[0][nl] + sSS[1][nl] + sSS[2][nl] + sSS[3][nl];
      float sc = 1.0f / fmaxf(sqrtf(tot), 1e-12f);
      out32[(size_t)(node0 + nl) * HID + wave * 16 + r15] = val[j] * sc;
    }
  }
}

extern "C" void kernel_launch(void* const* d_in, const int* in_sizes, int n_in,
                              void* d_out, int out_size, void* d_ws, size_t ws_size,
                              hipStream_t stream) {
  char* ws = (char*)d_ws;
  Args a;
  a.x  = (const float*)d_in[0];
  a.ei = (const int*)d_in[1];
  a.Wp = (const float*)d_in[2];  a.bp = (const float*)d_in[3];
  a.W1 = (const float*)d_in[4];  a.b1 = (const float*)d_in[5];
  a.W2 = (const float*)d_in[6];  a.b2 = (const float*)d_in[7];
  a.W3 = (const float*)d_in[8];  a.b3 = (const float*)d_in[9];
  a.out  = (float*)d_out;
  a.bufA16 = (_Float16*)(ws + 0);             // 12.8 MB fp16 activations A0
  a.hw16   = (_Float16*)(ws + 12800000);      // 12.8 MB fp16 activations A1
  a.pairs  = (int*)(ws + 25600000);           // 6.4 MB packed (dlocal<<17|src)
  a.csr    = (int*)(ws + 32000000);           // 6.4 MB (src byte offsets)
  a.offs   = (int*)(ws + 38400000);           // (N+1) ints
  a.dinv   = (float*)(ws + 38800016);         // 400 KB
  a.bsz    = (int*)(ws + 39200016);           // NB ints
  a.bboff  = (int*)(ws + 39203152);           // NB+1 ints
  a.bcur   = (int*)(ws + 39206288);           // NB ints
  a.WpH = (_Float16*)(ws + 39210000);         // 16 KB
  a.WpL = (_Float16*)(ws + 39226384);
  a.W1H = (_Float16*)(ws + 39242768);         // 8 KB each
  a.W1L = (_Float16*)(ws + 39250960);
  a.W2H = (_Float16*)(ws + 39259152);
  a.W2L = (_Float16*)(ws + 39267344);
  a.W3H = (_Float16*)(ws + 39275536);
  a.W3L = (_Float16*)(ws + 39283728);

  (void)hipMemsetAsync(a.bsz, 0, NB * sizeof(int), stream);
  f_prep<<<80, 256, 0, stream>>>(a);
  f_bhist<<<196, 256, 0, stream>>>(a);
  f_bscan<<<1, 256, 0, stream>>>(a);
  f_partition<<<196, 256, 0, stream>>>(a);
  f_csrdeg<<<NB, 256, 0, stream>>>(a);
  f_gemm_pre<<<NBLK_GEMM, 256, 0, stream>>>(a);
  f_aggw<0><<<NGROUP16, 256, 0, stream>>>(a, a.bufA16, a.W1H, a.W1L, a.b1, a.hw16, nullptr);
  f_aggw<0><<<NGROUP16, 256, 0, stream>>>(a, a.hw16, a.W2H, a.W2L, a.b2, a.bufA16, nullptr);
  f_aggw<1><<<NGROUP16, 256, 0, stream>>>(a, a.bufA16, a.W3H, a.W3L, a.b3, nullptr, a.out);
}